// Round 6
// baseline (1282.440 us; speedup 1.0000x reference)
//
#include <hip/hip_runtime.h>
#include <math.h>

typedef _Float16 half8  __attribute__((ext_vector_type(8)));
typedef _Float16 half4v __attribute__((ext_vector_type(4)));
typedef float    f32x16 __attribute__((ext_vector_type(16)));

namespace {
constexpr int H      = 4096;
constexpr int E      = 256;
constexpr int TOPK   = 8;
constexpr int NCAND  = 12;           // screened candidates per token
constexpr int BM     = 256;          // tokens per block (main kernel)
constexpr int BK     = 32;           // k per chunk
constexpr int NCHUNK = H / BK;       // 128
constexpr int SLD    = 256;          // score row stride (floats); lane*4 reads are
                                     // 16B/lane contiguous -> stride-agnostic
constexpr float DELTA = 5e-4f;       // near-tie rescue threshold (logit units)
constexpr size_t WF_BYTES = (size_t)E * H * 2 * 2;  // 4 MB: hi+lo fp16
// LDS: A dbuf = 2 x 32KB (256 tok x 32 k, hi/lo fp16) aliased with
// sc = 64 tok x 256 fp32 = 64KB.  max = 65536.
constexpr int SMEM_BYTES = 65536;
}

// ---------------- W pre-convert: fp32 -> fragment-ordered hi/lo fp16 --------
// Layout (halves): [grp(8)][ks(256)][hilo(2)][lane(64)][j(8)]
//   element W[e][k] (scaled by 64): grp=e>>5, ks=k>>4,
//   lane=(e&31) | (((k>>3)&1)<<5), j=k&7
__global__ void convert_w_kernel(const float* __restrict__ W,
                                 _Float16* __restrict__ Wf) {
    int t  = blockIdx.x * blockDim.x + threadIdx.x;
    int e  = t >> 10;
    int kq = t & 1023;           // k = kq*4
    float4 w4 = *(const float4*)(W + ((size_t)e << 12) + (kq << 2));
    float x0 = w4.x * 64.0f, x1 = w4.y * 64.0f, x2 = w4.z * 64.0f, x3 = w4.w * 64.0f;
    _Float16 h0 = (_Float16)x0, h1 = (_Float16)x1, h2 = (_Float16)x2, h3 = (_Float16)x3;
    _Float16 l0 = (_Float16)(x0 - (float)h0), l1 = (_Float16)(x1 - (float)h1);
    _Float16 l2 = (_Float16)(x2 - (float)h2), l3 = (_Float16)(x3 - (float)h3);
    int k    = kq << 2;
    int grp  = e >> 5;
    int ks   = k >> 4;
    int lane = (e & 31) | (((k >> 3) & 1) << 5);
    int j    = k & 7;            // 0 or 4
    size_t base = (((size_t)grp * 256 + ks) * 2) * 512 + lane * 8 + j;
    half4v hv = {h0, h1, h2, h3};
    half4v lv = {l0, l1, l2, l3};
    *(half4v*)(Wf + base)       = hv;   // hilo=0
    *(half4v*)(Wf + base + 512) = lv;   // hilo=1
}

// ---------------- main fused kernel: BM=256 split-fp16 MFMA GEMM + top8 -----
// Round-5 post-mortem: all small-BM variants latency-bound on B (Wf) traffic
// = (T/BM)*4MB with only ~48cyc MFMA/chunk/wave to hide it. BM=256 gives
// 48 MFMA/chunk/wave (8 acc tiles) vs 8 B-loads: compute now covers latency.
// 8 waves = 2M x 4N; wave (mr,wc) owns tokens 128*mr+.. x experts 64*wc+..
// A staged to LDS fragment-ordered hi/lo fp16 (round-0-proven recipe,
// mt generalized to 8 subtiles). One barrier per chunk. grid=256 = 1 blk/CU.
struct BReg { half8 h[2][2], l[2][2]; };  // [nt][ks]
struct X4   { float4 v[4]; };

__global__ __launch_bounds__(512, 1)
void moe_gate_mfma(const float* __restrict__ X, const _Float16* __restrict__ Wf,
                   const float* __restrict__ Wg,
                   float* __restrict__ out_idx, float* __restrict__ out_w) {
    __shared__ __align__(16) char smem[SMEM_BYTES];
    _Float16* Abuf = (_Float16*)smem;       // 2 buffers x 16384 halves
    float*    sc   = (float*)smem;          // epilogue scores [64][256]

    const int tid  = threadIdx.x;
    const int lane = tid & 63;
    const int wave = tid >> 6;      // 0..7
    const int mr   = wave >> 2;     // token half (0..1): tokens 128*mr..
    const int wc   = wave & 3;      // expert quarter (0..3): experts 64*wc..
    const int m0   = blockIdx.x * BM;

    // ---- staging map: thread stages 4 float4s (tokens q_tid3+64q, kq_s) ----
    const int q_tid3 = tid >> 3;          // 0..63
    const int kq_s   = tid & 7;           // k-quad 0..7 (k = kq_s*4)
    const int ks_s   = kq_s >> 2;         // k_step 0/1
    const int j_s    = (kq_s & 1) * 4;    // frag elem 0/4
    const int lane_s = (q_tid3 & 31) | (((kq_s >> 1) & 1) << 5);
    int dst_q[4];
    const float* xg_q[4];
    #pragma unroll
    for (int q = 0; q < 4; ++q) {
        const int mt = (q_tid3 >> 5) + 2 * q;       // token subtile 0..7
        dst_q[q] = ((ks_s * 8 + mt) * 2) * 512 + lane_s * 8 + j_s;
        xg_q[q]  = X + (size_t)(m0 + q_tid3 + 64 * q) * H + kq_s * 4;
    }

    const _Float16* wbase = Wf + (size_t)lane * 8;

    f32x16 acc[4][2];
    #pragma unroll
    for (int tl = 0; tl < 4; ++tl)
        #pragma unroll
        for (int nt = 0; nt < 2; ++nt)
            #pragma unroll
            for (int r = 0; r < 16; ++r) acc[tl][nt][r] = 0.0f;

    auto load_x = [&](int kc) {
        X4 x;
        #pragma unroll
        for (int q = 0; q < 4; ++q) x.v[q] = *(const float4*)(xg_q[q] + kc * BK);
        return x;
    };
    auto stage = [&](int bufIdx, const X4& x) {
        _Float16* buf = Abuf + bufIdx * 16384;
        #pragma unroll
        for (int q = 0; q < 4; ++q) {
            float x0 = x.v[q].x, x1 = x.v[q].y, x2 = x.v[q].z, x3 = x.v[q].w;
            _Float16 h0 = (_Float16)x0, h1 = (_Float16)x1,
                     h2 = (_Float16)x2, h3 = (_Float16)x3;
            _Float16 l0 = (_Float16)(x0 - (float)h0), l1 = (_Float16)(x1 - (float)h1);
            _Float16 l2 = (_Float16)(x2 - (float)h2), l3 = (_Float16)(x3 - (float)h3);
            half4v hv = {h0, h1, h2, h3};
            half4v lv = {l0, l1, l2, l3};
            *(half4v*)(buf + dst_q[q])       = hv;
            *(half4v*)(buf + dst_q[q] + 512) = lv;
        }
    };
    auto load_b = [&](int kc, BReg& b) {
        #pragma unroll
        for (int nt = 0; nt < 2; ++nt)
            #pragma unroll
            for (int ks = 0; ks < 2; ++ks) {
                size_t base = (((size_t)(2 * wc + nt) * 256 + (kc * 2 + ks)) * 2) * 512;
                b.h[nt][ks] = *(const half8*)(wbase + base);
                b.l[nt][ks] = *(const half8*)(wbase + base + 512);
            }
    };
    auto compute = [&](int bufIdx, const BReg& b) {
        const _Float16* buf = Abuf + bufIdx * 16384;
        #pragma unroll
        for (int ks = 0; ks < 2; ++ks)
            #pragma unroll
            for (int tl = 0; tl < 4; ++tl) {
                const _Float16* p = buf + ((ks * 8 + (mr * 4 + tl)) * 2) * 512 + lane * 8;
                half8 a_hi = *(const half8*)p;
                half8 a_lo = *(const half8*)(p + 512);
                #pragma unroll
                for (int nt = 0; nt < 2; ++nt) {
                    acc[tl][nt] = __builtin_amdgcn_mfma_f32_32x32x16_f16(a_hi, b.h[nt][ks], acc[tl][nt], 0, 0, 0);
                    acc[tl][nt] = __builtin_amdgcn_mfma_f32_32x32x16_f16(a_lo, b.h[nt][ks], acc[tl][nt], 0, 0, 0);
                    acc[tl][nt] = __builtin_amdgcn_mfma_f32_32x32x16_f16(a_hi, b.l[nt][ks], acc[tl][nt], 0, 0, 0);
                }
            }
    };

    // ---- prologue ----
    {
        X4 x0v = load_x(0);
        stage(0, x0v);
    }
    __syncthreads();

    // ---- K loop: one barrier per chunk; compute(~1500cyc/SIMD) covers the
    //      B-load (L2) and X-load (HBM) latencies issued at chunk top ----
    #pragma unroll 1
    for (int kc = 0; kc < NCHUNK; ++kc) {
        BReg b;
        load_b(kc, b);
        X4 xn;
        if (kc + 1 < NCHUNK) xn = load_x(kc + 1);
        compute(kc & 1, b);
        if (kc + 1 < NCHUNK) stage((kc + 1) & 1, xn);
        __syncthreads();
    }

    // ---- epilogue: 4 phases of 64 tokens through the 64KB sc buffer ----
    #pragma unroll
    for (int p = 0; p < 4; ++p) {
        if (mr == (p >> 1)) {   // wave-uniform
            #pragma unroll
            for (int s = 0; s < 2; ++s) {
                const int tl = (p & 1) * 2 + s;
                #pragma unroll
                for (int nt = 0; nt < 2; ++nt)
                    #pragma unroll
                    for (int r = 0; r < 16; ++r) {
                        int row = (r & 3) + 8 * (r >> 2) + 4 * (lane >> 5);
                        int col = lane & 31;
                        sc[(s * 32 + row) * SLD + wc * 64 + nt * 32 + col] =
                            acc[tl][nt][r] * 0.015625f;
                    }
            }
        }
        __syncthreads();

        // top-12 screen on logits + fp64 rescue for near-ties (round-0-proven)
        for (int t8 = 0; t8 < 8; ++t8) {
            const int t   = wave * 8 + t8;            // 0..63 within phase
            const int tok = m0 + p * 64 + t;          // global token
            float4 pv = *(const float4*)(sc + t * SLD + lane * 4);
            float p0 = pv.x, p1 = pv.y, p2 = pv.z, p3 = pv.w;

            float tv[NCAND]; int ti[NCAND];
            #pragma unroll
            for (int s = 0; s < NCAND; ++s) {
                float bv = p0; int bi = lane * 4;
                if (p1 > bv || (p1 == bv && lane * 4 + 1 < bi)) { bv = p1; bi = lane * 4 + 1; }
                if (p2 > bv || (p2 == bv && lane * 4 + 2 < bi)) { bv = p2; bi = lane * 4 + 2; }
                if (p3 > bv || (p3 == bv && lane * 4 + 3 < bi)) { bv = p3; bi = lane * 4 + 3; }
                #pragma unroll
                for (int off = 32; off > 0; off >>= 1) {
                    float ov = __shfl_xor(bv, off, 64);
                    int   oi = __shfl_xor(bi, off, 64);
                    if (ov > bv || (ov == bv && oi < bi)) { bv = ov; bi = oi; }
                }
                tv[s] = bv; ti[s] = bi;
                if ((bi >> 2) == lane) {
                    const int sl = bi & 3;
                    if      (sl == 0) p0 = -3e38f;
                    else if (sl == 1) p1 = -3e38f;
                    else if (sl == 2) p2 = -3e38f;
                    else              p3 = -3e38f;
                }
            }

            // near-tie detection among the decisive gaps (ranks 0-1 .. 8-9)
            bool rescue = false;
            #pragma unroll
            for (int g = 0; g < 9; ++g) rescue |= (tv[g] - tv[g + 1] < DELTA);

            if (rescue) {  // wave-uniform branch (tv identical across lanes)
                double dv[NCAND];
                const float* xr = X + (size_t)tok * H;
                #pragma unroll 1
                for (int c = 0; c < NCAND; ++c) {
                    const float* wrow = Wg + (size_t)ti[c] * H;
                    double s_ = 0.0;
                    #pragma unroll
                    for (int it = 0; it < 16; ++it) {
                        float4 xa = *(const float4*)(xr + it * 256 + lane * 4);
                        float4 wa = *(const float4*)(wrow + it * 256 + lane * 4);
                        s_ += (double)xa.x * wa.x + (double)xa.y * wa.y
                            + (double)xa.z * wa.z + (double)xa.w * wa.w;
                    }
                    #pragma unroll
                    for (int off = 32; off > 0; off >>= 1) s_ += __shfl_xor(s_, off, 64);
                    dv[c] = s_;
                }
                // exact selection sort of top 8 (desc, lower index on tie)
                int si[NCAND];
                #pragma unroll
                for (int c = 0; c < NCAND; ++c) si[c] = ti[c];
                #pragma unroll
                for (int a = 0; a < TOPK; ++a) {
                    int best = a;
                    #pragma unroll
                    for (int b2 = a + 1; b2 < NCAND; ++b2) {
                        if (dv[b2] > dv[best] || (dv[b2] == dv[best] && si[b2] < si[best])) best = b2;
                    }
                    double tdv = dv[a]; dv[a] = dv[best]; dv[best] = tdv;
                    int    tsi = si[a]; si[a] = si[best]; si[best] = tsi;
                }
                #pragma unroll
                for (int s = 0; s < TOPK; ++s) { tv[s] = (float)dv[s]; ti[s] = si[s]; }
            }

            if (lane == 0) {
                // weights = 2.5 * softmax over the top-8 logits (full-Z cancels)
                float M = tv[0];
                float e8[TOPK]; float den = 0.0f;
                #pragma unroll
                for (int s = 0; s < TOPK; ++s) { e8[s] = expf(tv[s] - M); den += e8[s]; }
                float scl = 2.5f / den;
                #pragma unroll
                for (int s = 0; s < TOPK; ++s) {
                    out_idx[(size_t)tok * TOPK + s] = (float)ti[s];
                    out_w[(size_t)tok * TOPK + s]   = e8[s] * scl;
                }
            }
        }
        __syncthreads();   // before next phase overwrites sc
    }
}

// ---------------- fallback (round-1 fp32 kernel, correctness-proven) --------
namespace fb {
constexpr int BM = 32, BK = 32;
constexpr int XS_LD = BM + 4, WS_LD = E + 4;
constexpr int LDS_FLOATS = BK * XS_LD + BK * WS_LD;
}

__global__ __launch_bounds__(256, 2)
void moe_gate_fallback(const float* __restrict__ X, const float* __restrict__ W,
                       float* __restrict__ out_idx, float* __restrict__ out_w) {
    __shared__ float lds[fb::LDS_FLOATS];
    float* xs = lds;
    float* ws = lds + fb::BK * fb::XS_LD;
    const int tid = threadIdx.x;
    const int tx = tid & 31, ty = tid >> 5;
    const int m0 = blockIdx.x * fb::BM;
    float acc[4][8];
    #pragma unroll
    for (int i = 0; i < 4; ++i)
        #pragma unroll
        for (int j = 0; j < 8; ++j) acc[i][j] = 0.0f;
    const int lr = tid >> 3, lc = (tid & 7) * 4;
    const float* xg = X + (size_t)(m0 + lr) * H + lc;
    const float* wg = W + (size_t)lr * H + lc;
    for (int kc = 0; kc < H; kc += fb::BK) {
        float4 xv = *(const float4*)(xg + kc);
        float4 wv[8];
        #pragma unroll
        for (int i = 0; i < 8; ++i) wv[i] = *(const float4*)(wg + (size_t)i * 32 * H + kc);
        __syncthreads();
        #pragma unroll
        for (int j = 0; j < 4; ++j) xs[(lc + j) * fb::XS_LD + lr] = ((const float*)&xv)[j];
        #pragma unroll
        for (int i = 0; i < 8; ++i)
            #pragma unroll
            for (int j = 0; j < 4; ++j)
                ws[(lc + j) * fb::WS_LD + i * 32 + lr] = ((const float*)&wv[i])[j];
        __syncthreads();
        #pragma unroll
        for (int kk = 0; kk < fb::BK; ++kk) {
            float4 xa = *(const float4*)(xs + kk * fb::XS_LD + ty * 4);
            float4 wb0 = *(const float4*)(ws + kk * fb::WS_LD + tx * 8);
            float4 wb1 = *(const float4*)(ws + kk * fb::WS_LD + tx * 8 + 4);
            const float xr[4] = {xa.x, xa.y, xa.z, xa.w};
            const float wr8[8] = {wb0.x, wb0.y, wb0.z, wb0.w, wb1.x, wb1.y, wb1.z, wb1.w};
            #pragma unroll
            for (int i = 0; i < 4; ++i)
                #pragma unroll
                for (int j = 0; j < 8; ++j) acc[i][j] = fmaf(xr[i], wr8[j], acc[i][j]);
        }
    }
    __syncthreads();
    float* sc = lds;
    #pragma unroll
    for (int i = 0; i < 4; ++i) {
        *(float4*)(sc + (ty * 4 + i) * fb::WS_LD + tx * 8) =
            make_float4(acc[i][0], acc[i][1], acc[i][2], acc[i][3]);
        *(float4*)(sc + (ty * 4 + i) * fb::WS_LD + tx * 8 + 4) =
            make_float4(acc[i][4], acc[i][5], acc[i][6], acc[i][7]);
    }
    __syncthreads();
    const int wave = tid >> 6, lane = tid & 63;
    for (int t8 = 0; t8 < 8; ++t8) {
        const int t = wave * 8 + t8;
        float4 pv = *(const float4*)(sc + t * fb::WS_LD + lane * 4);
        float v0 = pv.x, v1 = pv.y, v2 = pv.z, v3 = pv.w;
        float M = fmaxf(fmaxf(v0, v1), fmaxf(v2, v3));
        #pragma unroll
        for (int off = 32; off > 0; off >>= 1) M = fmaxf(M, __shfl_xor(M, off, 64));
        float p0 = expf(v0 - M), p1 = expf(v1 - M), p2 = expf(v2 - M), p3 = expf(v3 - M);
        float z = p0 + p1 + p2 + p3;
        #pragma unroll
        for (int off = 32; off > 0; off >>= 1) z += __shfl_xor(z, off, 64);
        p0 /= z; p1 /= z; p2 /= z; p3 /= z;
        float tv[TOPK]; int ti[TOPK];
        #pragma unroll
        for (int s = 0; s < TOPK; ++s) {
            float bv = p0; int bi = lane * 4;
            if (p1 > bv || (p1 == bv && lane * 4 + 1 < bi)) { bv = p1; bi = lane * 4 + 1; }
            if (p2 > bv || (p2 == bv && lane * 4 + 2 < bi)) { bv = p2; bi = lane * 4 + 2; }
            if (p3 > bv || (p3 == bv && lane * 4 + 3 < bi)) { bv = p3; bi = lane * 4 + 3; }
            #pragma unroll
            for (int off = 32; off > 0; off >>= 1) {
                float ov = __shfl_xor(bv, off, 64);
                int   oi = __shfl_xor(bi, off, 64);
                if (ov > bv || (ov == bv && oi < bi)) { bv = ov; bi = oi; }
            }
            tv[s] = bv; ti[s] = bi;
            if ((bi >> 2) == lane) {
                const int sl = bi & 3;
                if      (sl == 0) p0 = -1.0f;
                else if (sl == 1) p1 = -1.0f;
                else if (sl == 2) p2 = -1.0f;
                else              p3 = -1.0f;
            }
        }
        if (lane == 0) {
            float den = tv[0] + tv[1] + tv[2] + tv[3] + tv[4] + tv[5] + tv[6] + tv[7] + 1e-20f;
            float scl = 2.5f / den;
            size_t tok = (size_t)(m0 + t);
            #pragma unroll
            for (int s = 0; s < TOPK; ++s) {
                out_idx[tok * TOPK + s] = (float)ti[s];
                out_w[tok * TOPK + s]   = tv[s] * scl;
            }
        }
    }
}

extern "C" void kernel_launch(void* const* d_in, const int* in_sizes, int n_in,
                              void* d_out, int out_size, void* d_ws, size_t ws_size,
                              hipStream_t stream) {
    const float* X = (const float*)d_in[0];
    const float* W = (const float*)d_in[1];
    float* out = (float*)d_out;
    const int T = in_sizes[0] / H;
    float* out_idx = out;
    float* out_w   = out + (size_t)T * TOPK;

    if (ws_size >= WF_BYTES && (T % BM) == 0) {
        _Float16* Wf = (_Float16*)d_ws;
        hipLaunchKernelGGL(convert_w_kernel, dim3((E * (H / 4)) / 256), dim3(256), 0, stream, W, Wf);
        hipLaunchKernelGGL(moe_gate_mfma, dim3(T / BM), dim3(512), 0, stream, X, Wf, W, out_idx, out_w);
    } else {
        hipLaunchKernelGGL(moe_gate_fallback, dim3(T / fb::BM), dim3(256), 0, stream, X, W, out_idx, out_w);
    }
}

// Round 7
// 685.283 us; speedup vs baseline: 1.8714x; 1.8714x over previous
//
#include <hip/hip_runtime.h>
#include <math.h>

typedef _Float16 half8  __attribute__((ext_vector_type(8)));
typedef _Float16 half4v __attribute__((ext_vector_type(4)));
typedef float    f32x16 __attribute__((ext_vector_type(16)));

namespace {
constexpr int H      = 4096;
constexpr int E      = 256;
constexpr int TOPK   = 8;
constexpr int NCAND  = 12;           // screened candidates per token
constexpr int BM     = 64;           // tokens per block (main kernel)
constexpr int BK     = 32;           // k per chunk
constexpr int NCHUNK = H / BK;       // 128
constexpr int SLD    = E + 4;        // 260, score row stride (floats)
constexpr float DELTA = 5e-4f;       // near-tie rescue threshold (logit units)
constexpr size_t WF_BYTES = (size_t)E * H * 2 * 2;  // 4 MB: hi+lo fp16
constexpr int SMEM_BYTES = BM * SLD * 4;  // 66560 (A dbuf = 16 KB fits inside)
}

// ---------------- W pre-convert: fp32 -> fragment-ordered hi/lo fp16 --------
// Layout (halves): [nt(8)][ks(256)][hilo(2)][lane(64)][j(8)]
//   element W[e][k] (scaled by 64): nt=e>>5, ks=k>>4,
//   lane=(e&31) | (((k>>3)&1)<<5), j=k&7
__global__ void convert_w_kernel(const float* __restrict__ W,
                                 _Float16* __restrict__ Wf) {
    int t  = blockIdx.x * blockDim.x + threadIdx.x;
    int e  = t >> 10;
    int kq = t & 1023;           // k = kq*4
    float4 w4 = *(const float4*)(W + ((size_t)e << 12) + (kq << 2));
    float x0 = w4.x * 64.0f, x1 = w4.y * 64.0f, x2 = w4.z * 64.0f, x3 = w4.w * 64.0f;
    _Float16 h0 = (_Float16)x0, h1 = (_Float16)x1, h2 = (_Float16)x2, h3 = (_Float16)x3;
    _Float16 l0 = (_Float16)(x0 - (float)h0), l1 = (_Float16)(x1 - (float)h1);
    _Float16 l2 = (_Float16)(x2 - (float)h2), l3 = (_Float16)(x3 - (float)h3);
    int k    = kq << 2;
    int nt   = e >> 5;
    int ks   = k >> 4;
    int lane = (e & 31) | (((k >> 3) & 1) << 5);
    int j    = k & 7;            // 0 or 4
    size_t base = (((size_t)nt * 256 + ks) * 2) * 512 + lane * 8 + j;
    half4v hv = {h0, h1, h2, h3};
    half4v lv = {l0, l1, l2, l3};
    *(half4v*)(Wf + base)       = hv;   // hilo=0
    *(half4v*)(Wf + base + 512) = lv;   // hilo=1
}

// ---------------- main fused kernel: split-fp16 MFMA GEMM + top8 ------------
// Round-7 change vs the proven 483us round-0 kernel: the K-loop barrier is
// s_waitcnt lgkmcnt(0) + s_barrier (LDS-ordering only), NOT __syncthreads().
// __syncthreads emits s_waitcnt vmcnt(0), which drained the JUST-ISSUED
// next-chunk B/X prefetch loads every chunk -> serial 128 x full-mem-latency
// chain (rounds 0/4: ~9400 cyc/chunk regardless of occupancy). Leaving vmcnt
// floating lets the compiler emit counted vmcnt waits for the register
// dependencies, keeping prefetch loads in flight across the barrier (T4).
struct BF { half8 h[2][2]; half8 l[2][2]; };  // [k_step][n_tile]

__global__ __launch_bounds__(512, 2)
void moe_gate_mfma(const float* __restrict__ X, const _Float16* __restrict__ Wf,
                   const float* __restrict__ Wg,
                   float* __restrict__ out_idx, float* __restrict__ out_w) {
    __shared__ __align__(16) char smem[SMEM_BYTES];
    _Float16* Abuf = (_Float16*)smem;       // 2 buffers x 4096 halves
    float*    sc   = (float*)smem;          // epilogue scores [64][SLD]

    const int tid  = threadIdx.x;
    const int lane = tid & 63;
    const int wave = tid >> 6;      // 0..7
    const int wr   = wave >> 2;     // m half (0..1)
    const int wc   = wave & 3;      // n quarter (0..3), 64 experts each
    const int m0   = blockIdx.x * BM;

    // staging: thread -> (m_s, k = kq_s*4) of the 64x32 fp32 X tile
    const int m_s  = tid >> 3;      // 0..63
    const int kq_s = tid & 7;       // 0..7
    const int ks_s = kq_s >> 2;                              // k_step 0/1
    const int mt_s = m_s >> 5;                               // m tile 0/1
    const int ln_s = (m_s & 31) | (((kq_s >> 1) & 1) << 5);  // frag lane
    const int j_s  = (kq_s & 1) * 4;                         // frag elem 0/4
    const int dst_s = ((ks_s * 2 + mt_s) * 2) * 512 + ln_s * 8 + j_s;
    const float* xgp = X + (size_t)(m0 + m_s) * H + kq_s * 4;

    f32x16 acc[2];
    #pragma unroll
    for (int nt = 0; nt < 2; ++nt)
        #pragma unroll
        for (int r = 0; r < 16; ++r) acc[nt][r] = 0.0f;

    auto load_b = [&](int kc, BF& b) {
        #pragma unroll
        for (int ks = 0; ks < 2; ++ks)
            #pragma unroll
            for (int nt = 0; nt < 2; ++nt) {
                size_t base = (((size_t)(2 * wc + nt) * 256 + (kc * 2 + ks)) * 2) * 512
                              + lane * 8;
                b.h[ks][nt] = *(const half8*)(Wf + base);
                b.l[ks][nt] = *(const half8*)(Wf + base + 512);
            }
    };
    auto stage = [&](int bufIdx, float4 xv) {
        _Float16* buf = Abuf + bufIdx * 4096;
        float x0 = xv.x, x1 = xv.y, x2 = xv.z, x3 = xv.w;
        _Float16 h0 = (_Float16)x0, h1 = (_Float16)x1, h2 = (_Float16)x2, h3 = (_Float16)x3;
        _Float16 l0 = (_Float16)(x0 - (float)h0), l1 = (_Float16)(x1 - (float)h1);
        _Float16 l2 = (_Float16)(x2 - (float)h2), l3 = (_Float16)(x3 - (float)h3);
        half4v hv = {h0, h1, h2, h3};
        half4v lv = {l0, l1, l2, l3};
        *(half4v*)(buf + dst_s)       = hv;
        *(half4v*)(buf + dst_s + 512) = lv;
    };
    auto compute = [&](int bufIdx, const BF& b) {
        const _Float16* buf = Abuf + bufIdx * 4096;
        #pragma unroll
        for (int ks = 0; ks < 2; ++ks) {
            const _Float16* p = buf + (ks * 2 + wr) * 1024 + lane * 8;
            half8 a_hi = *(const half8*)p;
            half8 a_lo = *(const half8*)(p + 512);
            #pragma unroll
            for (int nt = 0; nt < 2; ++nt) {
                acc[nt] = __builtin_amdgcn_mfma_f32_32x32x16_f16(a_hi, b.h[ks][nt], acc[nt], 0, 0, 0);
                acc[nt] = __builtin_amdgcn_mfma_f32_32x32x16_f16(a_lo, b.h[ks][nt], acc[nt], 0, 0, 0);
                acc[nt] = __builtin_amdgcn_mfma_f32_32x32x16_f16(a_hi, b.l[ks][nt], acc[nt], 0, 0, 0);
            }
        }
    };

    // prologue
    BF bcur;
    load_b(0, bcur);
    float4 xv = *(const float4*)(xgp);
    stage(0, xv);
    __syncthreads();
    float4 xnxt = *(const float4*)(xgp + BK);

    for (int kc = 0; kc < NCHUNK; ++kc) {
        BF bnxt;
        float4 xfar = make_float4(0.f, 0.f, 0.f, 0.f);
        if (kc + 1 < NCHUNK) load_b(kc + 1, bnxt);
        if (kc + 2 < NCHUNK) xfar = *(const float4*)(xgp + (size_t)(kc + 2) * BK);
        compute(kc & 1, bcur);
        if (kc + 1 < NCHUNK) {
            stage((kc + 1) & 1, xnxt);
            // LDS-ordering barrier WITHOUT vmcnt(0): ds_writes drained, the
            // prefetch loads issued above stay in flight across the barrier.
            asm volatile("s_waitcnt lgkmcnt(0)" ::: "memory");
            __builtin_amdgcn_s_barrier();
        }
        bcur = bnxt;
        xnxt = xfar;
    }

    // -------- logits -> LDS (undo the x64 W prescale) --------
    __syncthreads();   // full drain: all waves done reading Abuf before alias
    #pragma unroll
    for (int nt = 0; nt < 2; ++nt) {
        #pragma unroll
        for (int r = 0; r < 16; ++r) {
            int row = (r & 3) + 8 * (r >> 2) + 4 * (lane >> 5);
            int col = lane & 31;
            sc[(wr * 32 + row) * SLD + wc * 64 + nt * 32 + col] = acc[nt][r] * 0.015625f;
        }
    }
    __syncthreads();

    // -------- top-12 screen on logits + fp64 rescue for near-ties -----------
    for (int t8 = 0; t8 < 8; ++t8) {
        const int t = wave * 8 + t8;
        float4 pv = *(const float4*)(sc + t * SLD + lane * 4);
        float p0 = pv.x, p1 = pv.y, p2 = pv.z, p3 = pv.w;

        float tv[NCAND]; int ti[NCAND];
        #pragma unroll
        for (int s = 0; s < NCAND; ++s) {
            float bv = p0; int bi = lane * 4;
            if (p1 > bv || (p1 == bv && lane * 4 + 1 < bi)) { bv = p1; bi = lane * 4 + 1; }
            if (p2 > bv || (p2 == bv && lane * 4 + 2 < bi)) { bv = p2; bi = lane * 4 + 2; }
            if (p3 > bv || (p3 == bv && lane * 4 + 3 < bi)) { bv = p3; bi = lane * 4 + 3; }
            #pragma unroll
            for (int off = 32; off > 0; off >>= 1) {
                float ov = __shfl_xor(bv, off, 64);
                int   oi = __shfl_xor(bi, off, 64);
                if (ov > bv || (ov == bv && oi < bi)) { bv = ov; bi = oi; }
            }
            tv[s] = bv; ti[s] = bi;
            if ((bi >> 2) == lane) {
                const int sl = bi & 3;
                if      (sl == 0) p0 = -3e38f;
                else if (sl == 1) p1 = -3e38f;
                else if (sl == 2) p2 = -3e38f;
                else              p3 = -3e38f;
            }
        }

        // near-tie detection among the decisive gaps (ranks 0-1 .. 8-9)
        bool rescue = false;
        #pragma unroll
        for (int g = 0; g < 9; ++g) rescue |= (tv[g] - tv[g + 1] < DELTA);

        if (rescue) {  // wave-uniform branch (tv identical across lanes)
            double dv[NCAND];
            const float* xr = X + (size_t)(m0 + t) * H;
            #pragma unroll 1
            for (int c = 0; c < NCAND; ++c) {
                const float* wrow = Wg + (size_t)ti[c] * H;
                double s_ = 0.0;
                #pragma unroll
                for (int it = 0; it < 16; ++it) {
                    float4 xa = *(const float4*)(xr + it * 256 + lane * 4);
                    float4 wa = *(const float4*)(wrow + it * 256 + lane * 4);
                    s_ += (double)xa.x * wa.x + (double)xa.y * wa.y
                        + (double)xa.z * wa.z + (double)xa.w * wa.w;
                }
                #pragma unroll
                for (int off = 32; off > 0; off >>= 1) s_ += __shfl_xor(s_, off, 64);
                dv[c] = s_;
            }
            // exact selection sort of top 8 (desc, lower index on tie)
            int si[NCAND];
            #pragma unroll
            for (int c = 0; c < NCAND; ++c) si[c] = ti[c];
            #pragma unroll
            for (int a = 0; a < TOPK; ++a) {
                int best = a;
                #pragma unroll
                for (int b = a + 1; b < NCAND; ++b) {
                    if (dv[b] > dv[best] || (dv[b] == dv[best] && si[b] < si[best])) best = b;
                }
                double tdv = dv[a]; dv[a] = dv[best]; dv[best] = tdv;
                int    tsi = si[a]; si[a] = si[best]; si[best] = tsi;
            }
            #pragma unroll
            for (int s = 0; s < TOPK; ++s) { tv[s] = (float)dv[s]; ti[s] = si[s]; }
        }

        if (lane == 0) {
            // weights = 2.5 * softmax over the top-8 logits (full-Z cancels)
            float M = tv[0];
            float e8[TOPK]; float den = 0.0f;
            #pragma unroll
            for (int s = 0; s < TOPK; ++s) { e8[s] = expf(tv[s] - M); den += e8[s]; }
            float scl = 2.5f / den;
            size_t tok = (size_t)(m0 + t);
            #pragma unroll
            for (int s = 0; s < TOPK; ++s) {
                out_idx[tok * TOPK + s] = (float)ti[s];
                out_w[tok * TOPK + s]   = e8[s] * scl;
            }
        }
    }
}

// ---------------- fallback (round-1 fp32 kernel, correctness-proven) --------
namespace fb {
constexpr int BM = 32, BK = 32;
constexpr int XS_LD = BM + 4, WS_LD = E + 4;
constexpr int LDS_FLOATS = BK * XS_LD + BK * WS_LD;
}

__global__ __launch_bounds__(256, 2)
void moe_gate_fallback(const float* __restrict__ X, const float* __restrict__ W,
                       float* __restrict__ out_idx, float* __restrict__ out_w) {
    __shared__ float lds[fb::LDS_FLOATS];
    float* xs = lds;
    float* ws = lds + fb::BK * fb::XS_LD;
    const int tid = threadIdx.x;
    const int tx = tid & 31, ty = tid >> 5;
    const int m0 = blockIdx.x * fb::BM;
    float acc[4][8];
    #pragma unroll
    for (int i = 0; i < 4; ++i)
        #pragma unroll
        for (int j = 0; j < 8; ++j) acc[i][j] = 0.0f;
    const int lr = tid >> 3, lc = (tid & 7) * 4;
    const float* xg = X + (size_t)(m0 + lr) * H + lc;
    const float* wg = W + (size_t)lr * H + lc;
    for (int kc = 0; kc < H; kc += fb::BK) {
        float4 xv = *(const float4*)(xg + kc);
        float4 wv[8];
        #pragma unroll
        for (int i = 0; i < 8; ++i) wv[i] = *(const float4*)(wg + (size_t)i * 32 * H + kc);
        __syncthreads();
        #pragma unroll
        for (int j = 0; j < 4; ++j) xs[(lc + j) * fb::XS_LD + lr] = ((const float*)&xv)[j];
        #pragma unroll
        for (int i = 0; i < 8; ++i)
            #pragma unroll
            for (int j = 0; j < 4; ++j)
                ws[(lc + j) * fb::WS_LD + i * 32 + lr] = ((const float*)&wv[i])[j];
        __syncthreads();
        #pragma unroll
        for (int kk = 0; kk < fb::BK; ++kk) {
            float4 xa = *(const float4*)(xs + kk * fb::XS_LD + ty * 4);
            float4 wb0 = *(const float4*)(ws + kk * fb::WS_LD + tx * 8);
            float4 wb1 = *(const float4*)(ws + kk * fb::WS_LD + tx * 8 + 4);
            const float xr[4] = {xa.x, xa.y, xa.z, xa.w};
            const float wr8[8] = {wb0.x, wb0.y, wb0.z, wb0.w, wb1.x, wb1.y, wb1.z, wb1.w};
            #pragma unroll
            for (int i = 0; i < 4; ++i)
                #pragma unroll
                for (int j = 0; j < 8; ++j) acc[i][j] = fmaf(xr[i], wr8[j], acc[i][j]);
        }
    }
    __syncthreads();
    float* sc = lds;
    #pragma unroll
    for (int i = 0; i < 4; ++i) {
        *(float4*)(sc + (ty * 4 + i) * fb::WS_LD + tx * 8) =
            make_float4(acc[i][0], acc[i][1], acc[i][2], acc[i][3]);
        *(float4*)(sc + (ty * 4 + i) * fb::WS_LD + tx * 8 + 4) =
            make_float4(acc[i][4], acc[i][5], acc[i][6], acc[i][7]);
    }
    __syncthreads();
    const int wave = tid >> 6, lane = tid & 63;
    for (int t8 = 0; t8 < 8; ++t8) {
        const int t = wave * 8 + t8;
        float4 pv = *(const float4*)(sc + t * fb::WS_LD + lane * 4);
        float v0 = pv.x, v1 = pv.y, v2 = pv.z, v3 = pv.w;
        float M = fmaxf(fmaxf(v0, v1), fmaxf(v2, v3));
        #pragma unroll
        for (int off = 32; off > 0; off >>= 1) M = fmaxf(M, __shfl_xor(M, off, 64));
        float p0 = expf(v0 - M), p1 = expf(v1 - M), p2 = expf(v2 - M), p3 = expf(v3 - M);
        float z = p0 + p1 + p2 + p3;
        #pragma unroll
        for (int off = 32; off > 0; off >>= 1) z += __shfl_xor(z, off, 64);
        p0 /= z; p1 /= z; p2 /= z; p3 /= z;
        float tv[TOPK]; int ti[TOPK];
        #pragma unroll
        for (int s = 0; s < TOPK; ++s) {
            float bv = p0; int bi = lane * 4;
            if (p1 > bv || (p1 == bv && lane * 4 + 1 < bi)) { bv = p1; bi = lane * 4 + 1; }
            if (p2 > bv || (p2 == bv && lane * 4 + 2 < bi)) { bv = p2; bi = lane * 4 + 2; }
            if (p3 > bv || (p3 == bv && lane * 4 + 3 < bi)) { bv = p3; bi = lane * 4 + 3; }
            #pragma unroll
            for (int off = 32; off > 0; off >>= 1) {
                float ov = __shfl_xor(bv, off, 64);
                int   oi = __shfl_xor(bi, off, 64);
                if (ov > bv || (ov == bv && oi < bi)) { bv = ov; bi = oi; }
            }
            tv[s] = bv; ti[s] = bi;
            if ((bi >> 2) == lane) {
                const int sl = bi & 3;
                if      (sl == 0) p0 = -1.0f;
                else if (sl == 1) p1 = -1.0f;
                else if (sl == 2) p2 = -1.0f;
                else              p3 = -1.0f;
            }
        }
        if (lane == 0) {
            float den = tv[0] + tv[1] + tv[2] + tv[3] + tv[4] + tv[5] + tv[6] + tv[7] + 1e-20f;
            float scl = 2.5f / den;
            size_t tok = (size_t)(m0 + t);
            #pragma unroll
            for (int s = 0; s < TOPK; ++s) {
                out_idx[tok * TOPK + s] = (float)ti[s];
                out_w[tok * TOPK + s]   = tv[s] * scl;
            }
        }
    }
}

extern "C" void kernel_launch(void* const* d_in, const int* in_sizes, int n_in,
                              void* d_out, int out_size, void* d_ws, size_t ws_size,
                              hipStream_t stream) {
    const float* X = (const float*)d_in[0];
    const float* W = (const float*)d_in[1];
    float* out = (float*)d_out;
    const int T = in_sizes[0] / H;
    float* out_idx = out;
    float* out_w   = out + (size_t)T * TOPK;

    if (ws_size >= WF_BYTES && (T % BM) == 0) {
        _Float16* Wf = (_Float16*)d_ws;
        hipLaunchKernelGGL(convert_w_kernel, dim3((E * (H / 4)) / 256), dim3(256), 0, stream, W, Wf);
        hipLaunchKernelGGL(moe_gate_mfma, dim3(T / BM), dim3(512), 0, stream, X, Wf, W, out_idx, out_w);
    } else {
        hipLaunchKernelGGL(moe_gate_fallback, dim3(T / fb::BM), dim3(256), 0, stream, X, W, out_idx, out_w);
    }
}

// Round 8
// 645.543 us; speedup vs baseline: 1.9866x; 1.0616x over previous
//
#include <hip/hip_runtime.h>
#include <math.h>

typedef _Float16 half8  __attribute__((ext_vector_type(8)));
typedef _Float16 half4v __attribute__((ext_vector_type(4)));
typedef float    f32x16 __attribute__((ext_vector_type(16)));

namespace {
constexpr int H      = 4096;
constexpr int E      = 256;
constexpr int TOPK   = 8;
constexpr int NCAND  = 12;           // screened candidates per token
constexpr int BM     = 64;           // tokens per block (main kernel)
constexpr int BK     = 32;           // k per chunk
constexpr int NCHUNK = H / BK;       // 128
constexpr int SLD    = E + 4;        // 260, score row stride (floats)
constexpr float DELTA = 5e-4f;       // near-tie rescue threshold (logit units)
constexpr size_t WF_BYTES = (size_t)E * H * 2 * 2;  // 4 MB: hi+lo fp16
constexpr int SMEM_BYTES = BM * SLD * 4;  // 66560 (A 4-buf = 32 KB aliases inside)
}

// ---------------- W pre-convert: fp32 -> fragment-ordered hi/lo fp16 --------
// Layout (halves): [grp(8)][ks(256)][hilo(2)][lane(64)][j(8)]
//   element W[e][k] (scaled by 64): grp=e>>5, ks=k>>4,
//   lane=(e&31) | (((k>>3)&1)<<5), j=k&7
__global__ void convert_w_kernel(const float* __restrict__ W,
                                 _Float16* __restrict__ Wf) {
    int t  = blockIdx.x * blockDim.x + threadIdx.x;
    int e  = t >> 10;
    int kq = t & 1023;           // k = kq*4
    float4 w4 = *(const float4*)(W + ((size_t)e << 12) + (kq << 2));
    float x0 = w4.x * 64.0f, x1 = w4.y * 64.0f, x2 = w4.z * 64.0f, x3 = w4.w * 64.0f;
    _Float16 h0 = (_Float16)x0, h1 = (_Float16)x1, h2 = (_Float16)x2, h3 = (_Float16)x3;
    _Float16 l0 = (_Float16)(x0 - (float)h0), l1 = (_Float16)(x1 - (float)h1);
    _Float16 l2 = (_Float16)(x2 - (float)h2), l3 = (_Float16)(x3 - (float)h3);
    int k    = kq << 2;
    int grp  = e >> 5;
    int ks   = k >> 4;
    int lane = (e & 31) | (((k >> 3) & 1) << 5);
    int j    = k & 7;            // 0 or 4
    size_t base = (((size_t)grp * 256 + ks) * 2) * 512 + lane * 8 + j;
    half4v hv = {h0, h1, h2, h3};
    half4v lv = {l0, l1, l2, l3};
    *(half4v*)(Wf + base)       = hv;   // hilo=0
    *(half4v*)(Wf + base + 512) = lv;   // hilo=1
}

// ---------------- main fused kernel: split-fp16 MFMA GEMM + top8 ------------
// Round-8 changes vs round-7 (432us, counted barrier proven):
//  (1) B de-dup: wave=wc owns a DISTINCT 32-expert slice (round-7's wr
//      mapping loaded every B slice twice per CU). B L2 traffic halved.
//  (2) B prefetch depth 2 (4 BF buffers in regs): issue-to-use distance
//      ~1 full 2-chunk iteration, covering loaded L2/L3 latency.
//  (3) Barrier every 2 chunks via 4-way LDS A rotation (32KB): half the
//      barrier/skew cost; 24 MFMA per barrier.
// K-loop barrier stays lgkmcnt-only (vmcnt floats across, T4).
struct BF { half8 h[2]; half8 l[2]; };  // [k_step], one 32-expert slice

__global__ __launch_bounds__(512, 2)
void moe_gate_mfma(const float* __restrict__ X, const _Float16* __restrict__ Wf,
                   const float* __restrict__ Wg,
                   float* __restrict__ out_idx, float* __restrict__ out_w) {
    __shared__ __align__(16) char smem[SMEM_BYTES];
    _Float16* Abuf = (_Float16*)smem;       // 4 buffers x 4096 halves (32 KB)
    float*    sc   = (float*)smem;          // epilogue scores [64][SLD]

    const int tid  = threadIdx.x;
    const int lane = tid & 63;
    const int wave = tid >> 6;      // 0..7 = expert slice (32 experts each)
    const int m0   = blockIdx.x * BM;

    // staging: thread -> (m_s, k = kq_s*4) of the 64x32 fp32 X tile
    const int m_s  = tid >> 3;      // 0..63
    const int kq_s = tid & 7;       // 0..7
    const int ks_s = kq_s >> 2;                              // k_step 0/1
    const int mt_s = m_s >> 5;                               // m tile 0/1
    const int ln_s = (m_s & 31) | (((kq_s >> 1) & 1) << 5);  // frag lane
    const int j_s  = (kq_s & 1) * 4;                         // frag elem 0/4
    const int dst_s = ((ks_s * 2 + mt_s) * 2) * 512 + ln_s * 8 + j_s;
    const float* xgp = X + (size_t)(m0 + m_s) * H + kq_s * 4;

    f32x16 acc[2];                  // [m_subtile]
    #pragma unroll
    for (int mt = 0; mt < 2; ++mt)
        #pragma unroll
        for (int r = 0; r < 16; ++r) acc[mt][r] = 0.0f;

    auto load_b = [&](int kc, BF& b) {
        #pragma unroll
        for (int ks = 0; ks < 2; ++ks) {
            size_t base = (((size_t)wave * 256 + (kc * 2 + ks)) * 2) * 512 + lane * 8;
            b.h[ks] = *(const half8*)(Wf + base);
            b.l[ks] = *(const half8*)(Wf + base + 512);
        }
    };
    auto ldx = [&](int kc) { return *(const float4*)(xgp + (size_t)kc * BK); };
    auto stage = [&](int bufIdx, float4 xv) {
        _Float16* buf = Abuf + bufIdx * 4096;
        float x0 = xv.x, x1 = xv.y, x2 = xv.z, x3 = xv.w;
        _Float16 h0 = (_Float16)x0, h1 = (_Float16)x1, h2 = (_Float16)x2, h3 = (_Float16)x3;
        _Float16 l0 = (_Float16)(x0 - (float)h0), l1 = (_Float16)(x1 - (float)h1);
        _Float16 l2 = (_Float16)(x2 - (float)h2), l3 = (_Float16)(x3 - (float)h3);
        half4v hv = {h0, h1, h2, h3};
        half4v lv = {l0, l1, l2, l3};
        *(half4v*)(buf + dst_s)       = hv;
        *(half4v*)(buf + dst_s + 512) = lv;
    };
    auto compute = [&](int bufIdx, const BF& b) {
        const _Float16* buf = Abuf + bufIdx * 4096;
        #pragma unroll
        for (int ks = 0; ks < 2; ++ks)
            #pragma unroll
            for (int mt = 0; mt < 2; ++mt) {
                const _Float16* p = buf + (ks * 2 + mt) * 1024 + lane * 8;
                half8 a_hi = *(const half8*)p;
                half8 a_lo = *(const half8*)(p + 512);
                acc[mt] = __builtin_amdgcn_mfma_f32_32x32x16_f16(a_hi, b.h[ks], acc[mt], 0, 0, 0);
                acc[mt] = __builtin_amdgcn_mfma_f32_32x32x16_f16(a_lo, b.h[ks], acc[mt], 0, 0, 0);
                acc[mt] = __builtin_amdgcn_mfma_f32_32x32x16_f16(a_hi, b.l[ks], acc[mt], 0, 0, 0);
            }
    };

    // prologue: chunks 0,1 staged; B for 0,1 in regs; X for 2,3 in flight
    BF b0, b1;
    load_b(0, b0); load_b(1, b1);
    stage(0, ldx(0)); stage(1, ldx(1));
    float4 xc0 = ldx(2), xc1 = ldx(3);
    __syncthreads();

    #pragma unroll 1
    for (int i = 0; i < NCHUNK / 2; ++i) {
        const int kc = 2 * i;                 // chunks kc, kc+1 this iter
        BF n0, n1; float4 xn0 = xc0, xn1 = xc1;
        const bool haveNext = (kc + 2 < NCHUNK);
        if (haveNext) { load_b(kc + 2, n0); load_b(kc + 3, n1); }
        if (kc + 4 < NCHUNK) { xn0 = ldx(kc + 4); xn1 = ldx(kc + 5); }
        compute(kc & 3, b0);
        compute((kc + 1) & 3, b1);
        if (haveNext) {
            stage((kc + 2) & 3, xc0);
            stage((kc + 3) & 3, xc1);
            // LDS-ordering barrier WITHOUT vmcnt(0): ds ops drained, the
            // prefetch loads issued above stay in flight across the barrier.
            asm volatile("s_waitcnt lgkmcnt(0)" ::: "memory");
            __builtin_amdgcn_s_barrier();
            b0 = n0; b1 = n1;
        }
        xc0 = xn0; xc1 = xn1;
    }

    // -------- logits -> LDS (undo the x64 W prescale) --------
    __syncthreads();   // full drain: all waves done reading Abuf before alias
    #pragma unroll
    for (int mt = 0; mt < 2; ++mt) {
        #pragma unroll
        for (int r = 0; r < 16; ++r) {
            int row = (r & 3) + 8 * (r >> 2) + 4 * (lane >> 5);
            int col = lane & 31;
            sc[(mt * 32 + row) * SLD + wave * 32 + col] = acc[mt][r] * 0.015625f;
        }
    }
    __syncthreads();

    // -------- top-12 screen on logits + fp64 rescue for near-ties -----------
    for (int t8 = 0; t8 < 8; ++t8) {
        const int t = wave * 8 + t8;
        float4 pv = *(const float4*)(sc + t * SLD + lane * 4);
        float p0 = pv.x, p1 = pv.y, p2 = pv.z, p3 = pv.w;

        float tv[NCAND]; int ti[NCAND];
        #pragma unroll
        for (int s = 0; s < NCAND; ++s) {
            float bv = p0; int bi = lane * 4;
            if (p1 > bv || (p1 == bv && lane * 4 + 1 < bi)) { bv = p1; bi = lane * 4 + 1; }
            if (p2 > bv || (p2 == bv && lane * 4 + 2 < bi)) { bv = p2; bi = lane * 4 + 2; }
            if (p3 > bv || (p3 == bv && lane * 4 + 3 < bi)) { bv = p3; bi = lane * 4 + 3; }
            #pragma unroll
            for (int off = 32; off > 0; off >>= 1) {
                float ov = __shfl_xor(bv, off, 64);
                int   oi = __shfl_xor(bi, off, 64);
                if (ov > bv || (ov == bv && oi < bi)) { bv = ov; bi = oi; }
            }
            tv[s] = bv; ti[s] = bi;
            if ((bi >> 2) == lane) {
                const int sl = bi & 3;
                if      (sl == 0) p0 = -3e38f;
                else if (sl == 1) p1 = -3e38f;
                else if (sl == 2) p2 = -3e38f;
                else              p3 = -3e38f;
            }
        }

        // near-tie detection among the decisive gaps (ranks 0-1 .. 8-9)
        bool rescue = false;
        #pragma unroll
        for (int g = 0; g < 9; ++g) rescue |= (tv[g] - tv[g + 1] < DELTA);

        if (rescue) {  // wave-uniform branch (tv identical across lanes)
            double dv[NCAND];
            const float* xr = X + (size_t)(m0 + t) * H;
            #pragma unroll 1
            for (int c = 0; c < NCAND; ++c) {
                const float* wrow = Wg + (size_t)ti[c] * H;
                double s_ = 0.0;
                #pragma unroll
                for (int it = 0; it < 16; ++it) {
                    float4 xa = *(const float4*)(xr + it * 256 + lane * 4);
                    float4 wa = *(const float4*)(wrow + it * 256 + lane * 4);
                    s_ += (double)xa.x * wa.x + (double)xa.y * wa.y
                        + (double)xa.z * wa.z + (double)xa.w * wa.w;
                }
                #pragma unroll
                for (int off = 32; off > 0; off >>= 1) s_ += __shfl_xor(s_, off, 64);
                dv[c] = s_;
            }
            // exact selection sort of top 8 (desc, lower index on tie)
            int si[NCAND];
            #pragma unroll
            for (int c = 0; c < NCAND; ++c) si[c] = ti[c];
            #pragma unroll
            for (int a = 0; a < TOPK; ++a) {
                int best = a;
                #pragma unroll
                for (int b = a + 1; b < NCAND; ++b) {
                    if (dv[b] > dv[best] || (dv[b] == dv[best] && si[b] < si[best])) best = b;
                }
                double tdv = dv[a]; dv[a] = dv[best]; dv[best] = tdv;
                int    tsi = si[a]; si[a] = si[best]; si[best] = tsi;
            }
            #pragma unroll
            for (int s = 0; s < TOPK; ++s) { tv[s] = (float)dv[s]; ti[s] = si[s]; }
        }

        if (lane == 0) {
            // weights = 2.5 * softmax over the top-8 logits (full-Z cancels)
            float M = tv[0];
            float e8[TOPK]; float den = 0.0f;
            #pragma unroll
            for (int s = 0; s < TOPK; ++s) { e8[s] = expf(tv[s] - M); den += e8[s]; }
            float scl = 2.5f / den;
            size_t tok = (size_t)(m0 + t);
            #pragma unroll
            for (int s = 0; s < TOPK; ++s) {
                out_idx[tok * TOPK + s] = (float)ti[s];
                out_w[tok * TOPK + s]   = e8[s] * scl;
            }
        }
    }
}

// ---------------- fallback (round-1 fp32 kernel, correctness-proven) --------
namespace fb {
constexpr int BM = 32, BK = 32;
constexpr int XS_LD = BM + 4, WS_LD = E + 4;
constexpr int LDS_FLOATS = BK * XS_LD + BK * WS_LD;
}

__global__ __launch_bounds__(256, 2)
void moe_gate_fallback(const float* __restrict__ X, const float* __restrict__ W,
                       float* __restrict__ out_idx, float* __restrict__ out_w) {
    __shared__ float lds[fb::LDS_FLOATS];
    float* xs = lds;
    float* ws = lds + fb::BK * fb::XS_LD;
    const int tid = threadIdx.x;
    const int tx = tid & 31, ty = tid >> 5;
    const int m0 = blockIdx.x * fb::BM;
    float acc[4][8];
    #pragma unroll
    for (int i = 0; i < 4; ++i)
        #pragma unroll
        for (int j = 0; j < 8; ++j) acc[i][j] = 0.0f;
    const int lr = tid >> 3, lc = (tid & 7) * 4;
    const float* xg = X + (size_t)(m0 + lr) * H + lc;
    const float* wg = W + (size_t)lr * H + lc;
    for (int kc = 0; kc < H; kc += fb::BK) {
        float4 xv = *(const float4*)(xg + kc);
        float4 wv[8];
        #pragma unroll
        for (int i = 0; i < 8; ++i) wv[i] = *(const float4*)(wg + (size_t)i * 32 * H + kc);
        __syncthreads();
        #pragma unroll
        for (int j = 0; j < 4; ++j) xs[(lc + j) * fb::XS_LD + lr] = ((const float*)&xv)[j];
        #pragma unroll
        for (int i = 0; i < 8; ++i)
            #pragma unroll
            for (int j = 0; j < 4; ++j)
                ws[(lc + j) * fb::WS_LD + i * 32 + lr] = ((const float*)&wv[i])[j];
        __syncthreads();
        #pragma unroll
        for (int kk = 0; kk < fb::BK; ++kk) {
            float4 xa = *(const float4*)(xs + kk * fb::XS_LD + ty * 4);
            float4 wb0 = *(const float4*)(ws + kk * fb::WS_LD + tx * 8);
            float4 wb1 = *(const float4*)(ws + kk * fb::WS_LD + tx * 8 + 4);
            const float xr[4] = {xa.x, xa.y, xa.z, xa.w};
            const float wr8[8] = {wb0.x, wb0.y, wb0.z, wb0.w, wb1.x, wb1.y, wb1.z, wb1.w};
            #pragma unroll
            for (int i = 0; i < 4; ++i)
                #pragma unroll
                for (int j = 0; j < 8; ++j) acc[i][j] = fmaf(xr[i], wr8[j], acc[i][j]);
        }
    }
    __syncthreads();
    float* sc = lds;
    #pragma unroll
    for (int i = 0; i < 4; ++i) {
        *(float4*)(sc + (ty * 4 + i) * fb::WS_LD + tx * 8) =
            make_float4(acc[i][0], acc[i][1], acc[i][2], acc[i][3]);
        *(float4*)(sc + (ty * 4 + i) * fb::WS_LD + tx * 8 + 4) =
            make_float4(acc[i][4], acc[i][5], acc[i][6], acc[i][7]);
    }
    __syncthreads();
    const int wave = tid >> 6, lane = tid & 63;
    for (int t8 = 0; t8 < 8; ++t8) {
        const int t = wave * 8 + t8;
        float4 pv = *(const float4*)(sc + t * fb::WS_LD + lane * 4);
        float v0 = pv.x, v1 = pv.y, v2 = pv.z, v3 = pv.w;
        float M = fmaxf(fmaxf(v0, v1), fmaxf(v2, v3));
        #pragma unroll
        for (int off = 32; off > 0; off >>= 1) M = fmaxf(M, __shfl_xor(M, off, 64));
        float p0 = expf(v0 - M), p1 = expf(v1 - M), p2 = expf(v2 - M), p3 = expf(v3 - M);
        float z = p0 + p1 + p2 + p3;
        #pragma unroll
        for (int off = 32; off > 0; off >>= 1) z += __shfl_xor(z, off, 64);
        p0 /= z; p1 /= z; p2 /= z; p3 /= z;
        float tv[TOPK]; int ti[TOPK];
        #pragma unroll
        for (int s = 0; s < TOPK; ++s) {
            float bv = p0; int bi = lane * 4;
            if (p1 > bv || (p1 == bv && lane * 4 + 1 < bi)) { bv = p1; bi = lane * 4 + 1; }
            if (p2 > bv || (p2 == bv && lane * 4 + 2 < bi)) { bv = p2; bi = lane * 4 + 2; }
            if (p3 > bv || (p3 == bv && lane * 4 + 3 < bi)) { bv = p3; bi = lane * 4 + 3; }
            #pragma unroll
            for (int off = 32; off > 0; off >>= 1) {
                float ov = __shfl_xor(bv, off, 64);
                int   oi = __shfl_xor(bi, off, 64);
                if (ov > bv || (ov == bv && oi < bi)) { bv = ov; bi = oi; }
            }
            tv[s] = bv; ti[s] = bi;
            if ((bi >> 2) == lane) {
                const int sl = bi & 3;
                if      (sl == 0) p0 = -1.0f;
                else if (sl == 1) p1 = -1.0f;
                else if (sl == 2) p2 = -1.0f;
                else              p3 = -1.0f;
            }
        }
        if (lane == 0) {
            float den = tv[0] + tv[1] + tv[2] + tv[3] + tv[4] + tv[5] + tv[6] + tv[7] + 1e-20f;
            float scl = 2.5f / den;
            size_t tok = (size_t)(m0 + t);
            #pragma unroll
            for (int s = 0; s < TOPK; ++s) {
                out_idx[tok * TOPK + s] = (float)ti[s];
                out_w[tok * TOPK + s]   = tv[s] * scl;
            }
        }
    }
}

extern "C" void kernel_launch(void* const* d_in, const int* in_sizes, int n_in,
                              void* d_out, int out_size, void* d_ws, size_t ws_size,
                              hipStream_t stream) {
    const float* X = (const float*)d_in[0];
    const float* W = (const float*)d_in[1];
    float* out = (float*)d_out;
    const int T = in_sizes[0] / H;
    float* out_idx = out;
    float* out_w   = out + (size_t)T * TOPK;

    if (ws_size >= WF_BYTES && (T % BM) == 0) {
        _Float16* Wf = (_Float16*)d_ws;
        hipLaunchKernelGGL(convert_w_kernel, dim3((E * (H / 4)) / 256), dim3(256), 0, stream, W, Wf);
        hipLaunchKernelGGL(moe_gate_mfma, dim3(T / BM), dim3(512), 0, stream, X, Wf, W, out_idx, out_w);
    } else {
        hipLaunchKernelGGL(moe_gate_fallback, dim3(T / fb::BM), dim3(256), 0, stream, X, W, out_idx, out_w);
    }
}